// Round 12
// baseline (270.974 us; speedup 1.0000x reference)
//
#include <hip/hip_runtime.h>

// LearnedSegmentEncoder on MI355X — tiled repack (linear read / scattered write)
// + tile-local MFMA GEMM. B=8, C=128, P=65536, D=64, S=32.
// Identity: pooled = conv2_w @ mean_seg(relu(conv1_w@x+b1)) + b2 (conv2 hoisted
// past the segment mean), so only conv1 runs per-pixel.
// Window-locality experiment: R2-R11 strided GEMM reads (window 16-32 MB/block)
// are stuck at ~0.8-1.4 TB/s regardless of schedule. Pass 1 repacks to
// [b][tile(1024px)][c][px] with LINEAR reads (the fast direction) and
// scattered 2KB WRITES (stores don't stall waves). Pass 2 = R9's GEMM with
// each block reading ONE contiguous 256KB region (tile-local c-stride 2KB).

#define B_ 8
#define C_ 128
#define P_ 65536
#define D_ 64
#define S_ 32
#define TPX 1024                 // pixels per tile
#define NT_ (P_ / TPX)           // 64 tiles per batch

typedef short bf16x8 __attribute__((ext_vector_type(8)));
typedef float f32x4  __attribute__((ext_vector_type(4)));
typedef float f32x4v __attribute__((ext_vector_type(4)));
typedef unsigned u32x4v __attribute__((ext_vector_type(4)));

__device__ __forceinline__ unsigned f2bfu(float f) {
  union { float f; unsigned u; } v; v.f = f;
  return (v.u + 0x7fffu + ((v.u >> 16) & 1u)) >> 16;   // RNE
}
__device__ __forceinline__ short f2bf(float f) { return (short)f2bfu(f); }

__global__ __launch_bounds__(256) void w1_to_bf16(const float* __restrict__ w1,
                                                  short* __restrict__ wbf) {
  int i = blockIdx.x * 256 + threadIdx.x;
  if (i < C_ * D_) wbf[i] = f2bf(w1[i]);
}

// Pass 1: grid (C, B). Block reads one (b,c) row LINEARLY (256 KB, nt loads),
// writes 64 tile-slots: ((b*64+t)*128 + c)*512 dwords, 2 KB contiguous each.
// Iteration i covers 2048 px = tiles {2i, 2i+half}: threads 0-127 -> tile 2i,
// threads 128-255 -> tile 2i+1; each thread 8 px = one u32x4 store.
__global__ __launch_bounds__(256) void repack_tiled(const float* __restrict__ feat,
                                                    unsigned* __restrict__ xbf) {
  const int c = blockIdx.x, b = blockIdx.y;
  const int tid = threadIdx.x, half = tid >> 7, lane = tid & 127;
  const f32x4v* rp = (const f32x4v*)(feat + ((size_t)b * C_ + c) * P_);

  #pragma unroll 2
  for (int i = 0; i < 32; ++i) {
    const int q = i * 512 + tid * 2;                   // float4 index in row
    const f32x4v a = __builtin_nontemporal_load(rp + q);
    const f32x4v d = __builtin_nontemporal_load(rp + q + 1);
    u32x4v o;
    o.x = f2bfu(a.x) | (f2bfu(a.y) << 16);
    o.y = f2bfu(a.z) | (f2bfu(a.w) << 16);
    o.z = f2bfu(d.x) | (f2bfu(d.y) << 16);
    o.w = f2bfu(d.z) | (f2bfu(d.w) << 16);
    const int t = 2 * i + half;
    *(u32x4v*)&xbf[(((size_t)b * NT_ + t) * C_ + c) * (TPX / 2) + lane * 4] = o;
  }
}

// Pass 2: grid (NT*2, B) = (128, 8) = 1024 blocks (4/CU), 256 thr = 4 waves.
// Block reads half of one 256KB tile region (contiguous!); wave owns 128 px
// as 4 tile-PAIRS of 32 px (even px -> tile-A, odd -> tile-B), one u32 load
// = 2 pixels. Tile-local channel stride = 512 dwords (2 KB).
__global__ __launch_bounds__(256, 4) void proj_tiled(
    const int* __restrict__ labels, const unsigned* __restrict__ xbf,
    const short* __restrict__ wbf, const float* __restrict__ b1,
    float* __restrict__ gsum, int* __restrict__ gcnt)
{
  __shared__ float s_acc[S_][68];                      // 8.5 KB
  __shared__ int   s_cnt[S_];

  const int tid = threadIdx.x;
  const int wave = tid >> 6, l = tid & 63, m = l & 15, g = l >> 4;
  const int tp = blockIdx.x >> 1, half = blockIdx.x & 1;
  const int b  = blockIdx.y;

  for (int i = tid; i < S_ * 68; i += 256) ((float*)s_acc)[i] = 0.f;
  if (tid < S_) s_cnt[tid] = 0;
  __syncthreads();

  bf16x8 bfr[4][4];
  #pragma unroll
  for (int nt = 0; nt < 4; ++nt)
    #pragma unroll
    for (int ks = 0; ks < 4; ++ks)
      bfr[nt][ks] = *(const bf16x8*)&wbf[(nt * 16 + m) * C_ + ks * 32 + g * 8];
  float b1v[4];
  #pragma unroll
  for (int nt = 0; nt < 4; ++nt) b1v[nt] = b1[nt * 16 + m];

  const unsigned* tb = xbf + ((size_t)b * NT_ + tp) * C_ * (TPX / 2);
  const int* lb = labels + (size_t)b * P_ + tp * TPX;

  for (int it = 0; it < 4; ++it) {
    const int pp = half * 512 + wave * 128 + it * 32;  // pair base (32 px, in-tile)
    f32x4 aA[4], aB[4];
    #pragma unroll
    for (int nt = 0; nt < 4; ++nt) {
      aA[nt] = (f32x4){0.f, 0.f, 0.f, 0.f};
      aB[nt] = (f32x4){0.f, 0.f, 0.f, 0.f};
    }

    #pragma unroll
    for (int ks = 0; ks < 4; ++ks) {
      bf16x8 afA, afB;
      const unsigned* xp = tb + (ks * 32 + g * 8) * (TPX / 2) + (pp >> 1) + m;
      #pragma unroll
      for (int j = 0; j < 8; ++j) {
        const unsigned v = xp[j * (TPX / 2)];
        afA[j] = (short)(v & 0xffffu);                 // even pixel
        afB[j] = (short)(v >> 16);                     // odd pixel
      }
      #pragma unroll
      for (int nt = 0; nt < 4; ++nt) {
        aA[nt] = __builtin_amdgcn_mfma_f32_16x16x32_bf16(afA, bfr[nt][ks], aA[nt], 0, 0, 0);
        aB[nt] = __builtin_amdgcn_mfma_f32_16x16x32_bf16(afB, bfr[nt][ks], aB[nt], 0, 0, 0);
      }
    }

    // C/D: d = nt*16 + m, row g*4+r -> pixels pp + 2*(g*4+r) (A) / +1 (B)
    #pragma unroll
    for (int r = 0; r < 4; ++r) {
      const int2 lv = *(const int2*)&lb[pp + 2 * (g * 4 + r)];
      const int lA = lv.x & (S_ - 1), lB = lv.y & (S_ - 1);
      #pragma unroll
      for (int nt = 0; nt < 4; ++nt) {
        atomicAdd(&s_acc[lA][nt * 16 + m], fmaxf(aA[nt][r] + b1v[nt], 0.f));
        atomicAdd(&s_acc[lB][nt * 16 + m], fmaxf(aB[nt][r] + b1v[nt], 0.f));
      }
    }
    if (m < 4) {
      const int2 lv = *(const int2*)&lb[pp + 2 * (g * 4 + m)];
      atomicAdd(&s_cnt[lv.x & (S_ - 1)], 1);
      atomicAdd(&s_cnt[lv.y & (S_ - 1)], 1);
    }
  }

  __syncthreads();
  for (int i = tid; i < S_ * D_; i += 256)
    atomicAdd(&gsum[(size_t)b * S_ * D_ + i], s_acc[i >> 6][i & 63]);
  if (tid < S_) atomicAdd(&gcnt[b * S_ + tid], s_cnt[tid]);
}

// Fallback (no workspace for xbf): R10's direct fp32 path, grid (P/512, B).
__global__ __launch_bounds__(256, 4) void proj_direct(
    const int* __restrict__ labels, const float* __restrict__ featf,
    const short* __restrict__ wbf, const float* __restrict__ b1,
    float* __restrict__ gsum, int* __restrict__ gcnt)
{
  __shared__ float s_acc[S_][68];
  __shared__ int   s_cnt[S_];

  const int tid = threadIdx.x;
  const int wave = tid >> 6, l = tid & 63, m = l & 15, g = l >> 4;
  const int b   = blockIdx.y;
  const int px0 = blockIdx.x * 512 + wave * 128;

  for (int i = tid; i < S_ * 68; i += 256) ((float*)s_acc)[i] = 0.f;
  if (tid < S_) s_cnt[tid] = 0;
  __syncthreads();

  bf16x8 bfr[4][4];
  #pragma unroll
  for (int nt = 0; nt < 4; ++nt)
    #pragma unroll
    for (int ks = 0; ks < 4; ++ks)
      bfr[nt][ks] = *(const bf16x8*)&wbf[(nt * 16 + m) * C_ + ks * 32 + g * 8];
  float b1v[4];
  #pragma unroll
  for (int nt = 0; nt < 4; ++nt) b1v[nt] = b1[nt * 16 + m];

  const int* lb = labels + (size_t)b * P_;

  for (int it = 0; it < 4; ++it) {
    const int pp = px0 + it * 32;
    f32x4 aA[4], aB[4];
    #pragma unroll
    for (int nt = 0; nt < 4; ++nt) {
      aA[nt] = (f32x4){0.f, 0.f, 0.f, 0.f};
      aB[nt] = (f32x4){0.f, 0.f, 0.f, 0.f};
    }
    #pragma unroll
    for (int ks = 0; ks < 4; ++ks) {
      bf16x8 afA, afB;
      const float* xp = featf + ((size_t)b * C_ + ks * 32 + g * 8) * P_ + pp + 2 * m;
      #pragma unroll
      for (int j = 0; j < 8; ++j) {
        afA[j] = f2bf(xp[(size_t)j * P_]);
        afB[j] = f2bf(xp[(size_t)j * P_ + 1]);
      }
      #pragma unroll
      for (int nt = 0; nt < 4; ++nt) {
        aA[nt] = __builtin_amdgcn_mfma_f32_16x16x32_bf16(afA, bfr[nt][ks], aA[nt], 0, 0, 0);
        aB[nt] = __builtin_amdgcn_mfma_f32_16x16x32_bf16(afB, bfr[nt][ks], aB[nt], 0, 0, 0);
      }
    }
    #pragma unroll
    for (int r = 0; r < 4; ++r) {
      const int2 lv = *(const int2*)&lb[pp + 2 * (g * 4 + r)];
      const int lA = lv.x & (S_ - 1), lB = lv.y & (S_ - 1);
      #pragma unroll
      for (int nt = 0; nt < 4; ++nt) {
        atomicAdd(&s_acc[lA][nt * 16 + m], fmaxf(aA[nt][r] + b1v[nt], 0.f));
        atomicAdd(&s_acc[lB][nt * 16 + m], fmaxf(aB[nt][r] + b1v[nt], 0.f));
      }
    }
    if (m < 4) {
      const int2 lv = *(const int2*)&lb[pp + 2 * (g * 4 + m)];
      atomicAdd(&s_cnt[lv.x & (S_ - 1)], 1);
      atomicAdd(&s_cnt[lv.y & (S_ - 1)], 1);
    }
  }

  __syncthreads();
  for (int i = tid; i < S_ * D_; i += 256)
    atomicAdd(&gsum[(size_t)b * S_ * D_ + i], s_acc[i >> 6][i & 63]);
  if (tid < S_) atomicAdd(&gcnt[b * S_ + tid], s_cnt[tid]);
}

// Grid (S, B), 64 lanes: all (b,s) blocks independent; ballot-based rank.
__global__ __launch_bounds__(64) void seg_finalize2(
    const float* __restrict__ gsum, const int* __restrict__ gcnt,
    const float* __restrict__ w2, const float* __restrict__ b2,
    const float* __restrict__ emb, const float* __restrict__ wo,
    const float* __restrict__ bo, float* __restrict__ out)
{
  const int s = blockIdx.x, b = blockIdx.y, o = threadIdx.x;
  const int co = (o < S_) ? gcnt[b * S_ + o] : 0;
  const unsigned long long mask = __ballot(co > 0);
  const int cnt = gcnt[b * S_ + s];
  if (cnt <= 0) return;                               // uniform exit
  const int rank = __popcll(mask & ((1ull << s) - 1ull));

  __shared__ float s_mean[D_], s_pool[D_];
  s_mean[o] = gsum[((size_t)b * S_ + s) * D_ + o] * (1.f / (float)cnt);
  __syncthreads();
  float pooled = b2[o];
  #pragma unroll
  for (int d = 0; d < D_; ++d) pooled += w2[o * D_ + d] * s_mean[d];
  s_pool[o] = pooled;
  __syncthreads();
  float r = bo[o];
  #pragma unroll
  for (int e = 0; e < D_; ++e) r += wo[o * 2 * D_ + e] * s_pool[e];
  #pragma unroll
  for (int e = 0; e < D_; ++e) r += wo[o * 2 * D_ + D_ + e] * emb[s * D_ + e];
  out[((size_t)b * S_ + rank) * D_ + o] = r;
}

extern "C" void kernel_launch(void* const* d_in, const int* in_sizes, int n_in,
                              void* d_out, int out_size, void* d_ws, size_t ws_size,
                              hipStream_t stream) {
  const int*   labels = (const int*)  d_in[0];
  const float* feat   = (const float*)d_in[1];
  const float* w1     = (const float*)d_in[2];
  const float* b1     = (const float*)d_in[3];
  const float* w2     = (const float*)d_in[4];
  const float* b2     = (const float*)d_in[5];
  const float* emb    = (const float*)d_in[6];
  const float* wo     = (const float*)d_in[7];
  const float* bo     = (const float*)d_in[8];
  float* out = (float*)d_out;

  // ws layout: gsum | gcnt | wbf | xbf (tiled bf16, 128 MB)
  char* w = (char*)d_ws;
  float*    gsum = (float*)w;    w += (size_t)B_ * S_ * D_ * 4;
  int*      gcnt = (int*)w;      w += (size_t)B_ * S_ * 4;
  short*    wbf  = (short*)w;    w += (size_t)C_ * D_ * 2;
  unsigned* xbf  = (unsigned*)w; w += (size_t)B_ * C_ * P_ * 2;
  const bool packed = ((size_t)(w - (char*)d_ws) <= ws_size);

  hipMemsetAsync(d_ws, 0, (size_t)B_ * S_ * D_ * 4 + (size_t)B_ * S_ * 4, stream);
  hipMemsetAsync(d_out, 0, (size_t)out_size * sizeof(float), stream);

  w1_to_bf16<<<(C_ * D_ + 255) / 256, 256, 0, stream>>>(w1, wbf);

  if (packed) {
    repack_tiled<<<dim3(C_, B_), 256, 0, stream>>>(feat, xbf);
    proj_tiled<<<dim3(NT_ * 2, B_), 256, 0, stream>>>(labels, xbf, wbf, b1, gsum, gcnt);
  } else {
    proj_direct<<<dim3(P_ / 512, B_), 256, 0, stream>>>(labels, feat, wbf, b1, gsum, gcnt);
  }
  seg_finalize2<<<dim3(S_, B_), 64, 0, stream>>>(gsum, gcnt, w2, b2, emb, wo, bo, out);
}

// Round 13
// 214.342 us; speedup vs baseline: 1.2642x; 1.2642x over previous
//
#include <hip/hip_runtime.h>

// LearnedSegmentEncoder on MI355X — quad-interleaved-tile MFMA GEMM with
// dwordx4 loads (4 pixels per lane per load). B=8, C=128, P=65536, D=64, S=32.
// Identity: pooled = conv2_w @ mean_seg(relu(conv1_w@x+b1)) + b2 (conv2 hoisted
// past the segment mean), so only conv1 runs per-pixel.
// Experiment: R2-R12 direct-load GEMMs all ran 190us with dword loads
// (4x64B lines/instr, ~4 lines in flight per CU). This kernel is identical
// except each load is a float4 = 4 consecutive pixels feeding 4 interleaved
// 16-px tiles -> 4x bytes and 4x cache lines per outstanding instruction.

#define B_ 8
#define C_ 128
#define P_ 65536
#define D_ 64
#define S_ 32

typedef short bf16x8 __attribute__((ext_vector_type(8)));
typedef float f32x4  __attribute__((ext_vector_type(4)));

__device__ __forceinline__ unsigned f2bfu(float f) {
  union { float f; unsigned u; } v; v.f = f;
  return (v.u + 0x7fffu + ((v.u >> 16) & 1u)) >> 16;   // RNE
}
__device__ __forceinline__ short f2bf(float f) { return (short)f2bfu(f); }

__global__ __launch_bounds__(256) void w1_to_bf16(const float* __restrict__ w1,
                                                  short* __restrict__ wbf) {
  int i = blockIdx.x * 256 + threadIdx.x;
  if (i < C_ * D_) wbf[i] = f2bf(w1[i]);
}

// Grid (P/512, B) = (128, 8) = 1024 blocks, 256 thr = 4 waves.
// Wave owns 128 px = 2 quad-groups of 64 px; quad-group = 4 interleaved
// 16-px tiles (tile i <- pixels qbase + 4*row + i). Lane (m,g) loads
// float4 at [c = ks*32+g*8+j][qbase + 4m]: per g-group 16 lanes x 16B =
// 256B contiguous; 4 x 256B segments per instruction.
__global__ __launch_bounds__(256, 2) void proj_quad(
    const int* __restrict__ labels, const float* __restrict__ feat,
    const short* __restrict__ wbf, const float* __restrict__ b1,
    float* __restrict__ gsum, int* __restrict__ gcnt)
{
  __shared__ float s_acc[S_][68];                      // 8.5 KB
  __shared__ int   s_cnt[S_];

  const int tid = threadIdx.x;
  const int wave = tid >> 6, l = tid & 63, m = l & 15, g = l >> 4;
  const int b   = blockIdx.y;
  const int px0 = blockIdx.x * 512 + wave * 128;

  for (int i = tid; i < S_ * 68; i += 256) ((float*)s_acc)[i] = 0.f;
  if (tid < S_) s_cnt[tid] = 0;
  __syncthreads();

  // W1^T B-fragments: bfr[nt][ks] = wbf[(nt*16+m)*C + ks*32 + g*8 ..+7]
  bf16x8 bfr[4][4];
  #pragma unroll
  for (int nt = 0; nt < 4; ++nt)
    #pragma unroll
    for (int ks = 0; ks < 4; ++ks)
      bfr[nt][ks] = *(const bf16x8*)&wbf[(nt * 16 + m) * C_ + ks * 32 + g * 8];
  float b1v[4];
  #pragma unroll
  for (int nt = 0; nt < 4; ++nt) b1v[nt] = b1[nt * 16 + m];

  const int* lb = labels + (size_t)b * P_;
  const float* xb = feat + (size_t)b * C_ * P_;

  #pragma unroll
  for (int qg = 0; qg < 2; ++qg) {
    const int qbase = px0 + qg * 64;

    f32x4 acc[4][4];                                   // [tile][nt]
    #pragma unroll
    for (int t = 0; t < 4; ++t)
      #pragma unroll
      for (int nt = 0; nt < 4; ++nt) acc[t][nt] = (f32x4){0.f, 0.f, 0.f, 0.f};

    #pragma unroll
    for (int ks = 0; ks < 4; ++ks) {
      // 8 float4 loads (1 KB/instr), then convert to 4 tile-fragments
      f32x4 xv[8];
      #pragma unroll
      for (int j = 0; j < 8; ++j)
        xv[j] = *(const f32x4*)&xb[(size_t)(ks * 32 + g * 8 + j) * P_
                                   + qbase + 4 * m];
      bf16x8 af[4];                                    // [tile]
      #pragma unroll
      for (int j = 0; j < 8; ++j) {
        af[0][j] = f2bf(xv[j][0]);
        af[1][j] = f2bf(xv[j][1]);
        af[2][j] = f2bf(xv[j][2]);
        af[3][j] = f2bf(xv[j][3]);
      }
      #pragma unroll
      for (int t = 0; t < 4; ++t)
        #pragma unroll
        for (int nt = 0; nt < 4; ++nt)
          acc[t][nt] = __builtin_amdgcn_mfma_f32_16x16x32_bf16(
              af[t], bfr[nt][ks], acc[t][nt], 0, 0, 0);
    }

    // C/D: d = nt*16 + m, row = g*4 + r -> pixel qbase + 4*(g*4+r) + t
    #pragma unroll
    for (int r = 0; r < 4; ++r) {
      const int4 lv = *(const int4*)&lb[qbase + 4 * (g * 4 + r)];
      const int labs[4] = { lv.x & (S_ - 1), lv.y & (S_ - 1),
                            lv.z & (S_ - 1), lv.w & (S_ - 1) };
      #pragma unroll
      for (int t = 0; t < 4; ++t)
        #pragma unroll
        for (int nt = 0; nt < 4; ++nt)
          atomicAdd(&s_acc[labs[t]][nt * 16 + m],
                    fmaxf(acc[t][nt][r] + b1v[nt], 0.f));
    }
    if (m < 4) {
      const int4 lv = *(const int4*)&lb[qbase + 4 * (g * 4 + m)];
      atomicAdd(&s_cnt[lv.x & (S_ - 1)], 1);
      atomicAdd(&s_cnt[lv.y & (S_ - 1)], 1);
      atomicAdd(&s_cnt[lv.z & (S_ - 1)], 1);
      atomicAdd(&s_cnt[lv.w & (S_ - 1)], 1);
    }
  }

  __syncthreads();
  for (int i = tid; i < S_ * D_; i += 256)
    atomicAdd(&gsum[(size_t)b * S_ * D_ + i], s_acc[i >> 6][i & 63]);
  if (tid < S_) atomicAdd(&gcnt[b * S_ + tid], s_cnt[tid]);
}

// Grid (S, B), 64 lanes: all (b,s) blocks independent; ballot-based rank.
__global__ __launch_bounds__(64) void seg_finalize2(
    const float* __restrict__ gsum, const int* __restrict__ gcnt,
    const float* __restrict__ w2, const float* __restrict__ b2,
    const float* __restrict__ emb, const float* __restrict__ wo,
    const float* __restrict__ bo, float* __restrict__ out)
{
  const int s = blockIdx.x, b = blockIdx.y, o = threadIdx.x;
  const int co = (o < S_) ? gcnt[b * S_ + o] : 0;
  const unsigned long long mask = __ballot(co > 0);
  const int cnt = gcnt[b * S_ + s];
  if (cnt <= 0) return;                               // uniform exit
  const int rank = __popcll(mask & ((1ull << s) - 1ull));

  __shared__ float s_mean[D_], s_pool[D_];
  s_mean[o] = gsum[((size_t)b * S_ + s) * D_ + o] * (1.f / (float)cnt);
  __syncthreads();
  float pooled = b2[o];
  #pragma unroll
  for (int d = 0; d < D_; ++d) pooled += w2[o * D_ + d] * s_mean[d];
  s_pool[o] = pooled;
  __syncthreads();
  float r = bo[o];
  #pragma unroll
  for (int e = 0; e < D_; ++e) r += wo[o * 2 * D_ + e] * s_pool[e];
  #pragma unroll
  for (int e = 0; e < D_; ++e) r += wo[o * 2 * D_ + D_ + e] * emb[s * D_ + e];
  out[((size_t)b * S_ + rank) * D_ + o] = r;
}

extern "C" void kernel_launch(void* const* d_in, const int* in_sizes, int n_in,
                              void* d_out, int out_size, void* d_ws, size_t ws_size,
                              hipStream_t stream) {
  const int*   labels = (const int*)  d_in[0];
  const float* feat   = (const float*)d_in[1];
  const float* w1     = (const float*)d_in[2];
  const float* b1     = (const float*)d_in[3];
  const float* w2     = (const float*)d_in[4];
  const float* b2     = (const float*)d_in[5];
  const float* emb    = (const float*)d_in[6];
  const float* wo     = (const float*)d_in[7];
  const float* bo     = (const float*)d_in[8];
  float* out = (float*)d_out;

  // ws layout: gsum | gcnt | wbf
  char* w = (char*)d_ws;
  float* gsum = (float*)w;   w += (size_t)B_ * S_ * D_ * 4;
  int*   gcnt = (int*)w;     w += (size_t)B_ * S_ * 4;
  short* wbf  = (short*)w;

  hipMemsetAsync(d_ws, 0, (size_t)B_ * S_ * D_ * 4 + (size_t)B_ * S_ * 4, stream);
  hipMemsetAsync(d_out, 0, (size_t)out_size * sizeof(float), stream);

  w1_to_bf16<<<(C_ * D_ + 255) / 256, 256, 0, stream>>>(w1, wbf);

  proj_quad<<<dim3(P_ / 512, B_), 256, 0, stream>>>(labels, feat, wbf, b1, gsum, gcnt);
  seg_finalize2<<<dim3(S_, B_), 64, 0, stream>>>(gsum, gcnt, w2, b2, emb, wo, bo, out);
}